// Round 1
// baseline (904.751 us; speedup 1.0000x reference)
//
#include <hip/hip_runtime.h>
#include <math.h>

#define SEQ     1024
#define NBATCH  8
#define NTOK    8192        // NBATCH*SEQ
#define DMODEL  512
#define DINNER  1024
#define NHEADS  16
#define DPROJ   2192
#define DPROJP  2304        // padded to multiple of 128
#define CONVDIM 1152
#define DFFN    2048

typedef short bf16x8 __attribute__((ext_vector_type(8)));
typedef float f32x4  __attribute__((ext_vector_type(4)));

__device__ inline unsigned short f2bf(float f) {
  union { float f; unsigned int u; } v; v.f = f;
  unsigned int u = v.u;
  return (unsigned short)((u + 0x7FFFu + ((u >> 16) & 1u)) >> 16);
}

// ---------------- bf16 conversion ----------------
__global__ __launch_bounds__(256) void cvt_bf16(const float* __restrict__ s,
                                                unsigned short* __restrict__ d, int n) {
  int i = blockIdx.x * 256 + threadIdx.x;
  if (i < n) d[i] = f2bf(s[i]);
}

__global__ __launch_bounds__(256) void cvt_bf16_pad(const float* __restrict__ s,
                                                    unsigned short* __restrict__ d,
                                                    int realrows, int cols, int padrows) {
  int i = blockIdx.x * 256 + threadIdx.x;
  if (i < padrows * cols) {
    int r = i / cols;
    d[i] = (r < realrows) ? f2bf(s[i]) : (unsigned short)0;
  }
}

// ---------------- bf16 MFMA GEMM: C[M,N] = A[M,K] @ B[N,K]^T ----------------
// 128x128 block tile, BK=32, 4 waves (2x2), each wave 64x64 via 4x4 of 16x16x32.
// MODE 0: fp32 store (+bias if non-null). MODE 1: bias + exact gelu -> bf16 store.
template <int MODE>
__global__ __launch_bounds__(256)
void gemm_bt(const unsigned short* __restrict__ A, const unsigned short* __restrict__ B,
             void* __restrict__ Cout, const float* __restrict__ bias, int K, int Nreal) {
  __shared__ unsigned short sA[128 * 32];
  __shared__ unsigned short sB[128 * 32];
  const int tid = threadIdx.x;
  const int bx = blockIdx.x, by = blockIdx.y;
  const int lane = tid & 63;
  const int wave = tid >> 6;
  const int wm = wave >> 1, wn = wave & 1;
  const int arow = tid >> 2;
  const int acol = (tid & 3) << 3;

  const unsigned short* pA = A + (size_t)(by * 128 + arow) * K + acol;
  const unsigned short* pB = B + (size_t)(bx * 128 + arow) * K + acol;
  const size_t stride64 = (size_t)64 * K;

  f32x4 acc[4][4];
#pragma unroll
  for (int i = 0; i < 4; i++)
#pragma unroll
    for (int j = 0; j < 4; j++) { f32x4 z = {0.f, 0.f, 0.f, 0.f}; acc[i][j] = z; }

  const int lrow = lane & 15;
  const int lkq = (lane >> 4) << 3;

  for (int k0 = 0; k0 < K; k0 += 32) {
    uint4 a0 = *(const uint4*)pA;
    uint4 a1 = *(const uint4*)(pA + stride64);
    uint4 b0 = *(const uint4*)pB;
    uint4 b1 = *(const uint4*)(pB + stride64);
    pA += 32; pB += 32;
    __syncthreads();
    *(uint4*)&sA[tid * 8] = a0;
    *(uint4*)&sA[tid * 8 + 2048] = a1;
    *(uint4*)&sB[tid * 8] = b0;
    *(uint4*)&sB[tid * 8 + 2048] = b1;
    __syncthreads();
    bf16x8 af[4], bfr[4];
#pragma unroll
    for (int mi = 0; mi < 4; mi++)
      af[mi] = *(const bf16x8*)&sA[(wm * 64 + mi * 16 + lrow) * 32 + lkq];
#pragma unroll
    for (int ni = 0; ni < 4; ni++)
      bfr[ni] = *(const bf16x8*)&sB[(wn * 64 + ni * 16 + lrow) * 32 + lkq];
#pragma unroll
    for (int mi = 0; mi < 4; mi++)
#pragma unroll
      for (int ni = 0; ni < 4; ni++)
        acc[mi][ni] = __builtin_amdgcn_mfma_f32_16x16x32_bf16(af[mi], bfr[ni], acc[mi][ni], 0, 0, 0);
  }

  const int row0 = by * 128 + wm * 64;
  const int col0 = bx * 128 + wn * 64;
#pragma unroll
  for (int mi = 0; mi < 4; mi++) {
#pragma unroll
    for (int ni = 0; ni < 4; ni++) {
      const int col = col0 + ni * 16 + lrow;
      if (col < Nreal) {
        const float bval = bias ? bias[col] : 0.f;
#pragma unroll
        for (int r = 0; r < 4; r++) {
          const int row = row0 + mi * 16 + ((lane >> 4) << 2) + r;
          float v = acc[mi][ni][r] + bval;
          if (MODE == 1) {
            float g = 0.5f * v * (1.f + erff(v * 0.7071067811865476f));
            ((unsigned short*)Cout)[(size_t)row * Nreal + col] = f2bf(g);
          } else {
            ((float*)Cout)[(size_t)row * Nreal + col] = v;
          }
        }
      }
    }
  }
}

// ---------------- dt = softplus(zx[...,2176+h] + dt_bias) (both dirs) ----------------
__global__ __launch_bounds__(256)
void dt_softplus(const float* __restrict__ zx, const float* __restrict__ dt_bias,
                 float* __restrict__ dtf, float* __restrict__ dtb) {
  int i = blockIdx.x * 256 + threadIdx.x;
  if (i >= 2 * NTOK * NHEADS) return;
  int dir = (i >= NTOK * NHEADS) ? 1 : 0;
  int r = i - dir * NTOK * NHEADS;
  int h = r & 15, bt = r >> 4;
  int b = bt >> 10, t = bt & 1023;
  int srow = (b << 10) + (dir ? (1023 - t) : t);
  float v = zx[(size_t)srow * DPROJ + 2176 + h] + dt_bias[h];
  float dt = (v > 20.f) ? v : log1pf(expf(v));
  (dir ? dtb : dtf)[bt * 16 + h] = dt;
}

// ---------------- causal depthwise conv (k=4) + silu (both dirs) ----------------
__global__ __launch_bounds__(256)
void conv_silu(const float* __restrict__ zx, const float* __restrict__ cw,
               const float* __restrict__ cb, float* __restrict__ xcf, float* __restrict__ xcb) {
  int dir = blockIdx.y;
  int i = blockIdx.x * 256 + threadIdx.x;
  if (i >= NTOK * CONVDIM) return;
  int c = i % CONVDIM;
  int bt = i / CONVDIM;
  int b = bt >> 10, t = bt & 1023;
  float acc = cb[c];
#pragma unroll
  for (int j = 0; j < 4; j++) {
    int tp = t - 3 + j;
    if (tp >= 0) {
      int srow = (b << 10) + (dir ? (1023 - tp) : tp);
      acc = fmaf(zx[(size_t)srow * DPROJ + DINNER + c], cw[c * 4 + j], acc);
    }
  }
  float r = acc / (1.f + expf(-acc));
  (dir ? xcb : xcf)[(size_t)bt * CONVDIM + c] = r;
}

// ---------------- SSD sequential scan: one block per (dir,b,h) ----------------
// threads: p = tid>>2 (0..63), ng = tid&3 -> 16 states each in registers.
__global__ __launch_bounds__(256)
void ssd_scan(const float* __restrict__ xcf, const float* __restrict__ xcb,
              const float* __restrict__ dtf, const float* __restrict__ dtb,
              const float* __restrict__ A_log, const float* __restrict__ Dp,
              float* __restrict__ yf, float* __restrict__ yb) {
  const int blk = blockIdx.x;
  const int dir = blk >> 7;
  const int b = (blk >> 4) & 7;
  const int h = blk & 15;
  const float* xc = dir ? xcb : xcf;
  const float* dtp = dir ? dtb : dtf;
  float* yo = dir ? yb : yf;
  const float A = -expf(A_log[h]);
  const float Dh = Dp[h];
  const int tid = threadIdx.x;
  const int p = tid >> 2;
  const int ng = tid & 3;
  const int bS = b << 10;
  __shared__ float sx[8][192];   // per step: x[64] | B[64] | C[64]
  __shared__ float sdt[8];
  float4 hs[4];
  hs[0] = hs[1] = hs[2] = hs[3] = make_float4(0.f, 0.f, 0.f, 0.f);

  for (int t0 = 0; t0 < SEQ; t0 += 8) {
    __syncthreads();
#pragma unroll
    for (int ii = 0; ii < 6; ii++) {
      int i = tid + ii * 256;
      int s2 = i / 192;
      int q = i - s2 * 192;
      int col = (q < 64) ? (h * 64 + q) : ((q < 128) ? (1024 + q - 64) : (1088 + q - 128));
      sx[s2][q] = xc[(size_t)(bS + t0 + s2) * CONVDIM + col];
    }
    if (tid < 8) sdt[tid] = dtp[(bS + t0 + tid) * 16 + h];
    __syncthreads();
#pragma unroll
    for (int s2 = 0; s2 < 8; s2++) {
      float dt = sdt[s2];
      float dA = expf(dt * A);
      float xp = sx[s2][p];
      float dtx = dt * xp;
      const float4* B4 = (const float4*)&sx[s2][64 + ng * 16];
      const float4* C4 = (const float4*)&sx[s2][128 + ng * 16];
      float yp = 0.f;
#pragma unroll
      for (int k = 0; k < 4; k++) {
        float4 bb = B4[k], cc = C4[k];
        hs[k].x = fmaf(hs[k].x, dA, bb.x * dtx); yp = fmaf(hs[k].x, cc.x, yp);
        hs[k].y = fmaf(hs[k].y, dA, bb.y * dtx); yp = fmaf(hs[k].y, cc.y, yp);
        hs[k].z = fmaf(hs[k].z, dA, bb.z * dtx); yp = fmaf(hs[k].z, cc.z, yp);
        hs[k].w = fmaf(hs[k].w, dA, bb.w * dtx); yp = fmaf(hs[k].w, cc.w, yp);
      }
      yp += __shfl_xor(yp, 1);
      yp += __shfl_xor(yp, 2);
      if (ng == 0)
        yo[(size_t)(bS + t0 + s2) * DINNER + h * 64 + p] = yp + xp * Dh;
    }
  }
}

// ---------------- block reduction (256 threads, 4 waves) ----------------
__device__ inline float2 block_sum2_256(float a, float b) {
#pragma unroll
  for (int o = 32; o >= 1; o >>= 1) { a += __shfl_xor(a, o); b += __shfl_xor(b, o); }
  __shared__ float ra[4], rb[4];
  const int lane = threadIdx.x & 63, w = threadIdx.x >> 6;
  if (lane == 0) { ra[w] = a; rb[w] = b; }
  __syncthreads();
  float2 out;
  out.x = ra[0] + ra[1] + ra[2] + ra[3];
  out.y = rb[0] + rb[1] + rb[2] + rb[3];
  return out;
}

// ---------------- g = y*silu(z); RMS-norm; -> bf16 ----------------
__global__ __launch_bounds__(256)
void gate_rms(const float* __restrict__ yf, const float* __restrict__ yb,
              const float* __restrict__ zx, const float* __restrict__ nw,
              unsigned short* __restrict__ gbf) {
  const int r = blockIdx.x;          // 0..16383 (dir-major)
  const int dir = r >> 13;
  const int bt = r & (NTOK - 1);
  const int b = bt >> 10, t = bt & 1023;
  const int zrow = (b << 10) + (dir ? (1023 - t) : t);
  const float* y = (dir ? yb : yf) + (size_t)bt * DINNER;
  const float* z = zx + (size_t)zrow * DPROJ;
  const int tid = threadIdx.x;
  float4 yv = *(const float4*)(y + tid * 4);
  float4 zv = *(const float4*)(z + tid * 4);
  float4 g;
  g.x = yv.x * (zv.x / (1.f + expf(-zv.x)));
  g.y = yv.y * (zv.y / (1.f + expf(-zv.y)));
  g.z = yv.z * (zv.z / (1.f + expf(-zv.z)));
  g.w = yv.w * (zv.w / (1.f + expf(-zv.w)));
  float2 sr = block_sum2_256(g.x * g.x + g.y * g.y + g.z * g.z + g.w * g.w, 0.f);
  float scale = rsqrtf(sr.x * (1.f / 1024.f) + 1e-5f);
  float4 wv = *(const float4*)(nw + tid * 4);
  unsigned short* o = gbf + (size_t)r * DINNER + tid * 4;
  o[0] = f2bf(g.x * scale * wv.x);
  o[1] = f2bf(g.y * scale * wv.y);
  o[2] = f2bf(g.z * scale * wv.z);
  o[3] = f2bf(g.w * scale * wv.w);
}

// ---------------- h = fwd + 0.5*bwd + u; layernorm -> fp32 + bf16 ----------------
__global__ __launch_bounds__(256)
void combine_ln(const float* __restrict__ mo, const float* __restrict__ u,
                const float* __restrict__ w, const float* __restrict__ bias,
                float* __restrict__ hln, unsigned short* __restrict__ hbf) {
  const int bt = blockIdx.x;
  const int tid = threadIdx.x;
  const float2 mf = *(const float2*)(mo + (size_t)bt * DMODEL + tid * 2);
  const float2 mb = *(const float2*)(mo + (size_t)(NTOK + bt) * DMODEL + tid * 2);
  const float2 uu = *(const float2*)(u + (size_t)bt * DMODEL + tid * 2);
  float vx = mf.x + 0.5f * mb.x + uu.x;
  float vy = mf.y + 0.5f * mb.y + uu.y;
  float2 sr = block_sum2_256(vx + vy, vx * vx + vy * vy);
  float mean = sr.x * (1.f / 512.f);
  float var = sr.y * (1.f / 512.f) - mean * mean;
  float inv = rsqrtf(var + 1e-12f);
  float2 wv = *(const float2*)(w + tid * 2);
  float2 bv = *(const float2*)(bias + tid * 2);
  float ox = (vx - mean) * inv * wv.x + bv.x;
  float oy = (vy - mean) * inv * wv.y + bv.y;
  *(float2*)(hln + (size_t)bt * DMODEL + tid * 2) = make_float2(ox, oy);
  hbf[(size_t)bt * DMODEL + tid * 2] = f2bf(ox);
  hbf[(size_t)bt * DMODEL + tid * 2 + 1] = f2bf(oy);
}

// ---------------- out = layernorm(f2 + hln) ----------------
__global__ __launch_bounds__(256)
void final_ln(const float* __restrict__ f2, const float* __restrict__ hln,
              const float* __restrict__ w, const float* __restrict__ bias,
              float* __restrict__ outp) {
  const int bt = blockIdx.x;
  const int tid = threadIdx.x;
  const float2 a = *(const float2*)(f2 + (size_t)bt * DMODEL + tid * 2);
  const float2 h = *(const float2*)(hln + (size_t)bt * DMODEL + tid * 2);
  float vx = a.x + h.x;
  float vy = a.y + h.y;
  float2 sr = block_sum2_256(vx + vy, vx * vx + vy * vy);
  float mean = sr.x * (1.f / 512.f);
  float var = sr.y * (1.f / 512.f) - mean * mean;
  float inv = rsqrtf(var + 1e-12f);
  float2 wv = *(const float2*)(w + tid * 2);
  float2 bv = *(const float2*)(bias + tid * 2);
  *(float2*)(outp + (size_t)bt * DMODEL + tid * 2) =
      make_float2((vx - mean) * inv * wv.x + bv.x, (vy - mean) * inv * wv.y + bv.y);
}

extern "C" void kernel_launch(void* const* d_in, const int* in_sizes, int n_in,
                              void* d_out, int out_size, void* d_ws, size_t ws_size,
                              hipStream_t stream) {
  const float* item_emb   = (const float*)d_in[0];
  const float* in_proj_w  = (const float*)d_in[3];
  const float* conv_w     = (const float*)d_in[4];
  const float* conv_b     = (const float*)d_in[5];
  const float* dt_bias    = (const float*)d_in[6];
  const float* A_log      = (const float*)d_in[7];
  const float* Dp         = (const float*)d_in[8];
  const float* norm_w     = (const float*)d_in[9];
  const float* out_proj_w = (const float*)d_in[10];
  const float* ln_w       = (const float*)d_in[11];
  const float* ln_b       = (const float*)d_in[12];
  const float* w1         = (const float*)d_in[13];
  const float* b1         = (const float*)d_in[14];
  const float* w2         = (const float*)d_in[15];
  const float* b2         = (const float*)d_in[16];
  const float* fln_w      = (const float*)d_in[17];
  const float* fln_b      = (const float*)d_in[18];
  float* outp = (float*)d_out;
  char* ws = (char*)d_ws;

  // workspace layout (phase-2 buffers alias phase-1 regions that are dead by then)
  const size_t o_ubf  = 0;                          // [8192,512]  bf16   8,388,608
  const size_t o_win  = o_ubf + 8388608;            // [2304,512]  bf16   2,359,296
  const size_t o_wout = o_win + 2359296;            // [512,1024]  bf16   1,048,576
  const size_t o_w1   = o_wout + 1048576;           // [2048,512]  bf16   2,097,152
  const size_t o_w2   = o_w1 + 2097152;             // [512,2048]  bf16   2,097,152
  const size_t o_dtf  = o_w2 + 2097152;             // [8192,16]   f32      524,288
  const size_t o_dtb  = o_dtf + 524288;
  const size_t o_zx   = o_dtb + 524288;             // [8192,2192] f32   71,827,456
  const size_t o_xcf  = o_zx + 71827456;            // [8192,1152] f32   37,748,736
  const size_t o_xcb  = o_xcf + 37748736;
  const size_t o_yf   = o_xcb + 37748736;           // [8192,1024] f32   33,554,432
  const size_t o_yb   = o_yf + 33554432;            // total 231,473,152 bytes
  const size_t o_gbf  = o_xcf;                      // [16384,1024] bf16 (xcf dead)
  const size_t o_mo   = o_zx;                       // [16384,512]  f32  (zx dead)
  const size_t o_hln  = o_zx + 33554432;            // [8192,512]   f32
  const size_t o_hbf  = o_zx + 50331648;            // [8192,512]   bf16
  const size_t o_h1   = o_xcb;                      // [8192,2048]  bf16 (xcb dead)
  const size_t o_f2   = o_yf;                       // [8192,512]   f32  (yf dead)

  unsigned short* u_bf  = (unsigned short*)(ws + o_ubf);
  unsigned short* winb  = (unsigned short*)(ws + o_win);
  unsigned short* woutb = (unsigned short*)(ws + o_wout);
  unsigned short* w1b   = (unsigned short*)(ws + o_w1);
  unsigned short* w2b   = (unsigned short*)(ws + o_w2);
  float* dtf = (float*)(ws + o_dtf);
  float* dtb = (float*)(ws + o_dtb);
  float* zx  = (float*)(ws + o_zx);
  float* xcf = (float*)(ws + o_xcf);
  float* xcb = (float*)(ws + o_xcb);
  float* yf  = (float*)(ws + o_yf);
  float* yb  = (float*)(ws + o_yb);
  unsigned short* gbf = (unsigned short*)(ws + o_gbf);
  float* mo  = (float*)(ws + o_mo);
  float* hln = (float*)(ws + o_hln);
  unsigned short* hbf = (unsigned short*)(ws + o_hbf);
  unsigned short* h1b = (unsigned short*)(ws + o_h1);
  float* f2  = (float*)(ws + o_f2);

  // ---- bf16 conversions ----
  {
    int n = NTOK * DMODEL;
    cvt_bf16<<<(n + 255) / 256, 256, 0, stream>>>(item_emb, u_bf, n);
    cvt_bf16_pad<<<(DPROJP * DMODEL + 255) / 256, 256, 0, stream>>>(in_proj_w, winb, DPROJ, DMODEL, DPROJP);
    n = DMODEL * DINNER;
    cvt_bf16<<<(n + 255) / 256, 256, 0, stream>>>(out_proj_w, woutb, n);
    n = DFFN * DMODEL;
    cvt_bf16<<<(n + 255) / 256, 256, 0, stream>>>(w1, w1b, n);
    n = DMODEL * DFFN;
    cvt_bf16<<<(n + 255) / 256, 256, 0, stream>>>(w2, w2b, n);
  }

  // ---- in-proj: zx[8192,2192] = u @ in_proj_w^T (shared by fwd & bwd) ----
  gemm_bt<0><<<dim3(DPROJP / 128, NTOK / 128), 256, 0, stream>>>(u_bf, winb, zx, nullptr, DMODEL, DPROJ);

  // ---- dt (softplus), conv+silu, both directions ----
  dt_softplus<<<(2 * NTOK * NHEADS + 255) / 256, 256, 0, stream>>>(zx, dt_bias, dtf, dtb);
  conv_silu<<<dim3((NTOK * CONVDIM + 255) / 256, 2), 256, 0, stream>>>(zx, conv_w, conv_b, xcf, xcb);

  // ---- SSD scan: 256 blocks = (dir,b,h) ----
  ssd_scan<<<256, 256, 0, stream>>>(xcf, xcb, dtf, dtb, A_log, Dp, yf, yb);

  // ---- gate + RMS norm -> bf16 [16384,1024] ----
  gate_rms<<<2 * NTOK, 256, 0, stream>>>(yf, yb, zx, norm_w, gbf);

  // ---- out-proj: mo[16384,512] = g @ out_proj_w^T ----
  gemm_bt<0><<<dim3(DMODEL / 128, 2 * NTOK / 128), 256, 0, stream>>>(gbf, woutb, mo, nullptr, DINNER, DMODEL);

  // ---- combine + first layernorm ----
  combine_ln<<<NTOK, 256, 0, stream>>>(mo, item_emb, ln_w, ln_b, hln, hbf);

  // ---- FFN ----
  gemm_bt<1><<<dim3(DFFN / 128, NTOK / 128), 256, 0, stream>>>(hbf, w1b, h1b, b1, DMODEL, DFFN);
  gemm_bt<0><<<dim3(DMODEL / 128, NTOK / 128), 256, 0, stream>>>(h1b, w2b, f2, b2, DFFN, DMODEL);

  // ---- final layernorm -> d_out ----
  final_ln<<<NTOK, 256, 0, stream>>>(f2, hln, fln_w, fln_b, outp);

  (void)in_sizes; (void)n_in; (void)out_size; (void)ws_size;
}

// Round 2
// 502.510 us; speedup vs baseline: 1.8005x; 1.8005x over previous
//
#include <hip/hip_runtime.h>
#include <math.h>

#define SEQ     1024
#define NBATCH  8
#define NTOK    8192        // NBATCH*SEQ
#define DMODEL  512
#define DINNER  1024
#define NHEADS  16
#define DPROJ   2192
#define DPROJP  2304        // padded to multiple of 128
#define CONVDIM 1152
#define DFFN    2048

typedef short bf16x8 __attribute__((ext_vector_type(8)));
typedef float f32x4  __attribute__((ext_vector_type(4)));

__device__ inline unsigned short f2bf(float f) {
  union { float f; unsigned int u; } v; v.f = f;
  unsigned int u = v.u;
  return (unsigned short)((u + 0x7FFFu + ((u >> 16) & 1u)) >> 16);
}
__device__ inline float bf2f(unsigned short s) {
  union { unsigned int u; float f; } v; v.u = ((unsigned int)s) << 16;
  return v.f;
}

// ---------------- bf16 conversion ----------------
__global__ __launch_bounds__(256) void cvt_bf16(const float* __restrict__ s,
                                                unsigned short* __restrict__ d, int n) {
  int i = blockIdx.x * 256 + threadIdx.x;
  if (i < n) d[i] = f2bf(s[i]);
}

__global__ __launch_bounds__(256) void cvt_bf16_pad(const float* __restrict__ s,
                                                    unsigned short* __restrict__ d,
                                                    int realrows, int cols, int padrows) {
  int i = blockIdx.x * 256 + threadIdx.x;
  if (i < padrows * cols) {
    int r = i / cols;
    d[i] = (r < realrows) ? f2bf(s[i]) : (unsigned short)0;
  }
}

// ---------------- bf16 MFMA GEMM: C[M,N] = A[M,K] @ B[N,K]^T ----------------
template <int MODE>
__global__ __launch_bounds__(256)
void gemm_bt(const unsigned short* __restrict__ A, const unsigned short* __restrict__ B,
             void* __restrict__ Cout, const float* __restrict__ bias, int K, int Nreal) {
  __shared__ unsigned short sA[128 * 32];
  __shared__ unsigned short sB[128 * 32];
  const int tid = threadIdx.x;
  const int bx = blockIdx.x, by = blockIdx.y;
  const int lane = tid & 63;
  const int wave = tid >> 6;
  const int wm = wave >> 1, wn = wave & 1;
  const int arow = tid >> 2;
  const int acol = (tid & 3) << 3;

  const unsigned short* pA = A + (size_t)(by * 128 + arow) * K + acol;
  const unsigned short* pB = B + (size_t)(bx * 128 + arow) * K + acol;
  const size_t stride64 = (size_t)64 * K;

  f32x4 acc[4][4];
#pragma unroll
  for (int i = 0; i < 4; i++)
#pragma unroll
    for (int j = 0; j < 4; j++) { f32x4 z = {0.f, 0.f, 0.f, 0.f}; acc[i][j] = z; }

  const int lrow = lane & 15;
  const int lkq = (lane >> 4) << 3;

  for (int k0 = 0; k0 < K; k0 += 32) {
    uint4 a0 = *(const uint4*)pA;
    uint4 a1 = *(const uint4*)(pA + stride64);
    uint4 b0 = *(const uint4*)pB;
    uint4 b1 = *(const uint4*)(pB + stride64);
    pA += 32; pB += 32;
    __syncthreads();
    *(uint4*)&sA[tid * 8] = a0;
    *(uint4*)&sA[tid * 8 + 2048] = a1;
    *(uint4*)&sB[tid * 8] = b0;
    *(uint4*)&sB[tid * 8 + 2048] = b1;
    __syncthreads();
    bf16x8 af[4], bfr[4];
#pragma unroll
    for (int mi = 0; mi < 4; mi++)
      af[mi] = *(const bf16x8*)&sA[(wm * 64 + mi * 16 + lrow) * 32 + lkq];
#pragma unroll
    for (int ni = 0; ni < 4; ni++)
      bfr[ni] = *(const bf16x8*)&sB[(wn * 64 + ni * 16 + lrow) * 32 + lkq];
#pragma unroll
    for (int mi = 0; mi < 4; mi++)
#pragma unroll
      for (int ni = 0; ni < 4; ni++)
        acc[mi][ni] = __builtin_amdgcn_mfma_f32_16x16x32_bf16(af[mi], bfr[ni], acc[mi][ni], 0, 0, 0);
  }

  const int row0 = by * 128 + wm * 64;
  const int col0 = bx * 128 + wn * 64;
#pragma unroll
  for (int mi = 0; mi < 4; mi++) {
#pragma unroll
    for (int ni = 0; ni < 4; ni++) {
      const int col = col0 + ni * 16 + lrow;
      if (col < Nreal) {
        const float bval = bias ? bias[col] : 0.f;
#pragma unroll
        for (int r = 0; r < 4; r++) {
          const int row = row0 + mi * 16 + ((lane >> 4) << 2) + r;
          float v = acc[mi][ni][r] + bval;
          if (MODE == 1) {
            float g = 0.5f * v * (1.f + erff(v * 0.7071067811865476f));
            ((unsigned short*)Cout)[(size_t)row * Nreal + col] = f2bf(g);
          } else {
            ((float*)Cout)[(size_t)row * Nreal + col] = v;
          }
        }
      }
    }
  }
}

// ---------------- dt = softplus(zx[...,2176+h] + dt_bias) (both dirs) ----------------
__global__ __launch_bounds__(256)
void dt_softplus(const float* __restrict__ zx, const float* __restrict__ dt_bias,
                 float* __restrict__ dtf, float* __restrict__ dtb) {
  int i = blockIdx.x * 256 + threadIdx.x;
  if (i >= 2 * NTOK * NHEADS) return;
  int dir = (i >= NTOK * NHEADS) ? 1 : 0;
  int r = i - dir * NTOK * NHEADS;
  int h = r & 15, bt = r >> 4;
  int b = bt >> 10, t = bt & 1023;
  int srow = (b << 10) + (dir ? (1023 - t) : t);
  float v = zx[(size_t)srow * DPROJ + 2176 + h] + dt_bias[h];
  float dt = (v > 20.f) ? v : log1pf(expf(v));
  (dir ? dtb : dtf)[bt * 16 + h] = dt;
}

// ---------------- causal depthwise conv (k=4) + silu (both dirs) ----------------
__global__ __launch_bounds__(256)
void conv_silu(const float* __restrict__ zx, const float* __restrict__ cw,
               const float* __restrict__ cb, float* __restrict__ xcf, float* __restrict__ xcb) {
  int dir = blockIdx.y;
  int i = blockIdx.x * 256 + threadIdx.x;
  if (i >= NTOK * CONVDIM) return;
  int c = i % CONVDIM;
  int bt = i / CONVDIM;
  int b = bt >> 10, t = bt & 1023;
  float acc = cb[c];
#pragma unroll
  for (int j = 0; j < 4; j++) {
    int tp = t - 3 + j;
    if (tp >= 0) {
      int srow = (b << 10) + (dir ? (1023 - tp) : tp);
      acc = fmaf(zx[(size_t)srow * DPROJ + DINNER + c], cw[c * 4 + j], acc);
    }
  }
  float r = acc / (1.f + expf(-acc));
  (dir ? xcb : xcf)[(size_t)bt * CONVDIM + c] = r;
}

// ---------------- chunked SSD: one block per (dir,b,h), 16 chunks of L=64 ----------------
// Per chunk (all MFMA 16x16x32 bf16, fp32 accum):
//   M1 = C @ B^T                        (64x64, K=64)
//   M  = mask(M1): s<=i -> M1*exp(L_i-L_s)*dt_s
//   Y  = M @ X  +  exp(L_i) * (C @ h^T) + D*x
//   S  = X^T @ (B * dt_s*exp(L63-L_s)) ; h = exp(L63)*h + S   (fp32 regs)
__global__ __launch_bounds__(256)
void ssd_chunk(const float* __restrict__ xcf, const float* __restrict__ xcb,
               const float* __restrict__ dtf, const float* __restrict__ dtb,
               const float* __restrict__ A_log, const float* __restrict__ Dp,
               float* __restrict__ yf, float* __restrict__ yb) {
  const int blk = blockIdx.x;
  const int dir = blk >> 7;
  const int b = (blk >> 4) & 7;
  const int h = blk & 15;
  const float* xc = dir ? xcb : xcf;
  const float* dtp = dir ? dtb : dtf;
  float* yo = dir ? yb : yf;
  const float A = -expf(A_log[h]);
  const float Dh = Dp[h];
  const int tid = threadIdx.x;
  const int lane = tid & 63;
  const int w = tid >> 6;          // wave 0..3 -> 16-row output stripe
  const int lrow = lane & 15;
  const int quad = lane >> 4;
  const int lk8 = quad << 3;
  const int bS = b << 10;

  // bf16 tiles, row stride 72 (=144B: 16B-aligned rows, 36-bank rotation -> <=2-way)
  __shared__ unsigned short Cb[64 * 72];   // [i][n]
  __shared__ unsigned short Bb[64 * 72];   // [s][n]
  __shared__ unsigned short Xt[64 * 72];   // [p][s]
  __shared__ unsigned short Bw[64 * 72];   // [n][s]  (decay/dt weighted)
  __shared__ unsigned short Mb[64 * 72];   // [i][s]  (masked)
  __shared__ unsigned short Hb[64 * 72];   // [p][n]  (h_init, bf16)
  __shared__ float sXf[64 * 68];           // [s][p]  fp32 (D-term)

  f32x4 hacc[4];                           // h[p= w*16+quad*4+r][n= j*16+lrow]
#pragma unroll
  for (int j = 0; j < 4; j++) { f32x4 z = {0.f, 0.f, 0.f, 0.f}; hacc[j] = z; }

  for (int c = 0; c < 16; c++) {
    const int t0 = c << 6;
    __syncthreads();                       // protect LDS from previous chunk's readers

    // stage h_init -> LDS (bf16)
#pragma unroll
    for (int j = 0; j < 4; j++)
#pragma unroll
      for (int r = 0; r < 4; r++)
        Hb[(w * 16 + quad * 4 + r) * 72 + j * 16 + lrow] = f2bf(hacc[j][r]);

    // stage x/B/C rows t0..t0+63 -> LDS
#pragma unroll
    for (int k = 0; k < 4; k++) {
      int idx = tid + k * 256;
      int s = idx >> 4, q = idx & 15;
      const float* rowp = xc + (size_t)(bS + t0 + s) * CONVDIM;
      float4 vx = *(const float4*)(rowp + h * 64 + q * 4);
      float4 vb = *(const float4*)(rowp + 1024 + q * 4);
      float4 vc = *(const float4*)(rowp + 1088 + q * 4);
      *(float4*)&sXf[s * 68 + q * 4] = vx;
      Xt[(q * 4 + 0) * 72 + s] = f2bf(vx.x);
      Xt[(q * 4 + 1) * 72 + s] = f2bf(vx.y);
      Xt[(q * 4 + 2) * 72 + s] = f2bf(vx.z);
      Xt[(q * 4 + 3) * 72 + s] = f2bf(vx.w);
      ushort4 b4; b4.x = f2bf(vb.x); b4.y = f2bf(vb.y); b4.z = f2bf(vb.z); b4.w = f2bf(vb.w);
      *(ushort4*)&Bb[s * 72 + q * 4] = b4;
      ushort4 c4; c4.x = f2bf(vc.x); c4.y = f2bf(vc.y); c4.z = f2bf(vc.z); c4.w = f2bf(vc.w);
      *(ushort4*)&Cb[s * 72 + q * 4] = c4;
    }
    float dtl = dtp[(bS + t0 + lane) * 16 + h];   // lane l holds dt_{t0+l}
    __syncthreads();

    // per-wave inclusive prefix scan of dt over 64 lanes (redundant per wave)
    float v = dtl;
#pragma unroll
    for (int off = 1; off < 64; off <<= 1) {
      float o = __shfl_up(v, off);
      if (lane >= off) v += o;
    }
    const float Lv = A * v;                 // L_lane (<=0)
    const float ev = expf(Lv);
    const float LL = __shfl(Lv, 63);
    const float wv = dtl * expf(LL - Lv);   // state weight for s=lane

    // Bw[n][s] = B[s][n] * wv_s   (s = lane, n = w + 4k)
#pragma unroll
    for (int k = 0; k < 16; k++) {
      int n = w + 4 * k;
      Bw[n * 72 + lane] = f2bf(bf2f(Bb[lane * 72 + n]) * wv);
    }

    // GEMM1: M1[i in stripe][s]
    f32x4 m1[4];
#pragma unroll
    for (int j = 0; j < 4; j++) { f32x4 z = {0.f, 0.f, 0.f, 0.f}; m1[j] = z; }
#pragma unroll
    for (int kq = 0; kq < 2; kq++) {
      bf16x8 af = *(const bf16x8*)&Cb[(w * 16 + lrow) * 72 + kq * 32 + lk8];
#pragma unroll
      for (int j = 0; j < 4; j++) {
        bf16x8 bf = *(const bf16x8*)&Bb[(j * 16 + lrow) * 72 + kq * 32 + lk8];
        m1[j] = __builtin_amdgcn_mfma_f32_16x16x32_bf16(af, bf, m1[j], 0, 0, 0);
      }
    }
    // mask + decay -> Mb
#pragma unroll
    for (int r = 0; r < 4; r++) {
      int i = w * 16 + quad * 4 + r;
      float Li = __shfl(Lv, i);
#pragma unroll
      for (int j = 0; j < 4; j++) {
        int s = j * 16 + lrow;
        float Ls = __shfl(Lv, s);
        float ds = __shfl(dtl, s);
        float val = (s <= i) ? m1[j][r] * expf(Li - Ls) * ds : 0.f;
        Mb[i * 72 + s] = f2bf(val);
      }
    }
    __syncthreads();

    // GEMM2: Y = M@X ; GEMM2b: T = C@H^T ; GEMM3: S = Xt@Bw^T
    f32x4 Y[4], T[4], S[4];
#pragma unroll
    for (int j = 0; j < 4; j++) {
      f32x4 z = {0.f, 0.f, 0.f, 0.f};
      Y[j] = z; T[j] = z; S[j] = z;
    }
#pragma unroll
    for (int kq = 0; kq < 2; kq++) {
      bf16x8 am = *(const bf16x8*)&Mb[(w * 16 + lrow) * 72 + kq * 32 + lk8];
      bf16x8 ac = *(const bf16x8*)&Cb[(w * 16 + lrow) * 72 + kq * 32 + lk8];
      bf16x8 ax = *(const bf16x8*)&Xt[(w * 16 + lrow) * 72 + kq * 32 + lk8];
#pragma unroll
      for (int j = 0; j < 4; j++) {
        bf16x8 bx = *(const bf16x8*)&Xt[(j * 16 + lrow) * 72 + kq * 32 + lk8];
        bf16x8 bh = *(const bf16x8*)&Hb[(j * 16 + lrow) * 72 + kq * 32 + lk8];
        bf16x8 bw = *(const bf16x8*)&Bw[(j * 16 + lrow) * 72 + kq * 32 + lk8];
        Y[j] = __builtin_amdgcn_mfma_f32_16x16x32_bf16(am, bx, Y[j], 0, 0, 0);
        T[j] = __builtin_amdgcn_mfma_f32_16x16x32_bf16(ac, bh, T[j], 0, 0, 0);
        S[j] = __builtin_amdgcn_mfma_f32_16x16x32_bf16(ax, bw, S[j], 0, 0, 0);
      }
    }

    // combine + store Y, update h
    const float dtot = expf(LL);
#pragma unroll
    for (int r = 0; r < 4; r++) {
      int i = w * 16 + quad * 4 + r;
      float ei = __shfl(ev, i);
#pragma unroll
      for (int j = 0; j < 4; j++) {
        int p = j * 16 + lrow;
        float yv = Y[j][r] + ei * T[j][r] + Dh * sXf[i * 68 + p];
        yo[(size_t)(bS + t0 + i) * DINNER + h * 64 + p] = yv;
      }
    }
#pragma unroll
    for (int j = 0; j < 4; j++)
#pragma unroll
      for (int r = 0; r < 4; r++)
        hacc[j][r] = dtot * hacc[j][r] + S[j][r];
  }
}

// ---------------- block reduction (256 threads, 4 waves) ----------------
__device__ inline float2 block_sum2_256(float a, float b) {
#pragma unroll
  for (int o = 32; o >= 1; o >>= 1) { a += __shfl_xor(a, o); b += __shfl_xor(b, o); }
  __shared__ float ra[4], rb[4];
  const int lane = threadIdx.x & 63, w = threadIdx.x >> 6;
  if (lane == 0) { ra[w] = a; rb[w] = b; }
  __syncthreads();
  float2 out;
  out.x = ra[0] + ra[1] + ra[2] + ra[3];
  out.y = rb[0] + rb[1] + rb[2] + rb[3];
  return out;
}

// ---------------- g = y*silu(z); RMS-norm; -> bf16 ----------------
__global__ __launch_bounds__(256)
void gate_rms(const float* __restrict__ yf, const float* __restrict__ yb,
              const float* __restrict__ zx, const float* __restrict__ nw,
              unsigned short* __restrict__ gbf) {
  const int r = blockIdx.x;          // 0..16383 (dir-major)
  const int dir = r >> 13;
  const int bt = r & (NTOK - 1);
  const int b = bt >> 10, t = bt & 1023;
  const int zrow = (b << 10) + (dir ? (1023 - t) : t);
  const float* y = (dir ? yb : yf) + (size_t)bt * DINNER;
  const float* z = zx + (size_t)zrow * DPROJ;
  const int tid = threadIdx.x;
  float4 yv = *(const float4*)(y + tid * 4);
  float4 zv = *(const float4*)(z + tid * 4);
  float4 g;
  g.x = yv.x * (zv.x / (1.f + expf(-zv.x)));
  g.y = yv.y * (zv.y / (1.f + expf(-zv.y)));
  g.z = yv.z * (zv.z / (1.f + expf(-zv.z)));
  g.w = yv.w * (zv.w / (1.f + expf(-zv.w)));
  float2 sr = block_sum2_256(g.x * g.x + g.y * g.y + g.z * g.z + g.w * g.w, 0.f);
  float scale = rsqrtf(sr.x * (1.f / 1024.f) + 1e-5f);
  float4 wv = *(const float4*)(nw + tid * 4);
  unsigned short* o = gbf + (size_t)r * DINNER + tid * 4;
  o[0] = f2bf(g.x * scale * wv.x);
  o[1] = f2bf(g.y * scale * wv.y);
  o[2] = f2bf(g.z * scale * wv.z);
  o[3] = f2bf(g.w * scale * wv.w);
}

// ---------------- h = fwd + 0.5*bwd + u; layernorm -> fp32 + bf16 ----------------
__global__ __launch_bounds__(256)
void combine_ln(const float* __restrict__ mo, const float* __restrict__ u,
                const float* __restrict__ w, const float* __restrict__ bias,
                float* __restrict__ hln, unsigned short* __restrict__ hbf) {
  const int bt = blockIdx.x;
  const int tid = threadIdx.x;
  const float2 mf = *(const float2*)(mo + (size_t)bt * DMODEL + tid * 2);
  const float2 mb = *(const float2*)(mo + (size_t)(NTOK + bt) * DMODEL + tid * 2);
  const float2 uu = *(const float2*)(u + (size_t)bt * DMODEL + tid * 2);
  float vx = mf.x + 0.5f * mb.x + uu.x;
  float vy = mf.y + 0.5f * mb.y + uu.y;
  float2 sr = block_sum2_256(vx + vy, vx * vx + vy * vy);
  float mean = sr.x * (1.f / 512.f);
  float var = sr.y * (1.f / 512.f) - mean * mean;
  float inv = rsqrtf(var + 1e-12f);
  float2 wv = *(const float2*)(w + tid * 2);
  float2 bv = *(const float2*)(bias + tid * 2);
  float ox = (vx - mean) * inv * wv.x + bv.x;
  float oy = (vy - mean) * inv * wv.y + bv.y;
  *(float2*)(hln + (size_t)bt * DMODEL + tid * 2) = make_float2(ox, oy);
  hbf[(size_t)bt * DMODEL + tid * 2] = f2bf(ox);
  hbf[(size_t)bt * DMODEL + tid * 2 + 1] = f2bf(oy);
}

// ---------------- out = layernorm(f2 + hln) ----------------
__global__ __launch_bounds__(256)
void final_ln(const float* __restrict__ f2, const float* __restrict__ hln,
              const float* __restrict__ w, const float* __restrict__ bias,
              float* __restrict__ outp) {
  const int bt = blockIdx.x;
  const int tid = threadIdx.x;
  const float2 a = *(const float2*)(f2 + (size_t)bt * DMODEL + tid * 2);
  const float2 h = *(const float2*)(hln + (size_t)bt * DMODEL + tid * 2);
  float vx = a.x + h.x;
  float vy = a.y + h.y;
  float2 sr = block_sum2_256(vx + vy, vx * vx + vy * vy);
  float mean = sr.x * (1.f / 512.f);
  float var = sr.y * (1.f / 512.f) - mean * mean;
  float inv = rsqrtf(var + 1e-12f);
  float2 wv = *(const float2*)(w + tid * 2);
  float2 bv = *(const float2*)(bias + tid * 2);
  *(float2*)(outp + (size_t)bt * DMODEL + tid * 2) =
      make_float2((vx - mean) * inv * wv.x + bv.x, (vy - mean) * inv * wv.y + bv.y);
}

extern "C" void kernel_launch(void* const* d_in, const int* in_sizes, int n_in,
                              void* d_out, int out_size, void* d_ws, size_t ws_size,
                              hipStream_t stream) {
  const float* item_emb   = (const float*)d_in[0];
  const float* in_proj_w  = (const float*)d_in[3];
  const float* conv_w     = (const float*)d_in[4];
  const float* conv_b     = (const float*)d_in[5];
  const float* dt_bias    = (const float*)d_in[6];
  const float* A_log      = (const float*)d_in[7];
  const float* Dp         = (const float*)d_in[8];
  const float* norm_w     = (const float*)d_in[9];
  const float* out_proj_w = (const float*)d_in[10];
  const float* ln_w       = (const float*)d_in[11];
  const float* ln_b       = (const float*)d_in[12];
  const float* w1         = (const float*)d_in[13];
  const float* b1         = (const float*)d_in[14];
  const float* w2         = (const float*)d_in[15];
  const float* b2         = (const float*)d_in[16];
  const float* fln_w      = (const float*)d_in[17];
  const float* fln_b      = (const float*)d_in[18];
  float* outp = (float*)d_out;
  char* ws = (char*)d_ws;

  // workspace layout (phase-2 buffers alias phase-1 regions that are dead by then)
  const size_t o_ubf  = 0;                          // [8192,512]  bf16   8,388,608
  const size_t o_win  = o_ubf + 8388608;            // [2304,512]  bf16   2,359,296
  const size_t o_wout = o_win + 2359296;            // [512,1024]  bf16   1,048,576
  const size_t o_w1   = o_wout + 1048576;           // [2048,512]  bf16   2,097,152
  const size_t o_w2   = o_w1 + 2097152;             // [512,2048]  bf16   2,097,152
  const size_t o_dtf  = o_w2 + 2097152;             // [8192,16]   f32      524,288
  const size_t o_dtb  = o_dtf + 524288;
  const size_t o_zx   = o_dtb + 524288;             // [8192,2192] f32   71,827,456
  const size_t o_xcf  = o_zx + 71827456;            // [8192,1152] f32   37,748,736
  const size_t o_xcb  = o_xcf + 37748736;
  const size_t o_yf   = o_xcb + 37748736;           // [8192,1024] f32   33,554,432
  const size_t o_yb   = o_yf + 33554432;            // total 231,473,152 bytes
  const size_t o_gbf  = o_xcf;                      // [16384,1024] bf16 (xcf dead)
  const size_t o_mo   = o_zx;                       // [16384,512]  f32  (zx dead)
  const size_t o_hln  = o_zx + 33554432;            // [8192,512]   f32
  const size_t o_hbf  = o_zx + 50331648;            // [8192,512]   bf16
  const size_t o_h1   = o_xcb;                      // [8192,2048]  bf16 (xcb dead)
  const size_t o_f2   = o_yf;                       // [8192,512]   f32  (yf dead)

  unsigned short* u_bf  = (unsigned short*)(ws + o_ubf);
  unsigned short* winb  = (unsigned short*)(ws + o_win);
  unsigned short* woutb = (unsigned short*)(ws + o_wout);
  unsigned short* w1b   = (unsigned short*)(ws + o_w1);
  unsigned short* w2b   = (unsigned short*)(ws + o_w2);
  float* dtf = (float*)(ws + o_dtf);
  float* dtb = (float*)(ws + o_dtb);
  float* zx  = (float*)(ws + o_zx);
  float* xcf = (float*)(ws + o_xcf);
  float* xcb = (float*)(ws + o_xcb);
  float* yf  = (float*)(ws + o_yf);
  float* yb  = (float*)(ws + o_yb);
  unsigned short* gbf = (unsigned short*)(ws + o_gbf);
  float* mo  = (float*)(ws + o_mo);
  float* hln = (float*)(ws + o_hln);
  unsigned short* hbf = (unsigned short*)(ws + o_hbf);
  unsigned short* h1b = (unsigned short*)(ws + o_h1);
  float* f2  = (float*)(ws + o_f2);

  // ---- bf16 conversions ----
  {
    int n = NTOK * DMODEL;
    cvt_bf16<<<(n + 255) / 256, 256, 0, stream>>>(item_emb, u_bf, n);
    cvt_bf16_pad<<<(DPROJP * DMODEL + 255) / 256, 256, 0, stream>>>(in_proj_w, winb, DPROJ, DMODEL, DPROJP);
    n = DMODEL * DINNER;
    cvt_bf16<<<(n + 255) / 256, 256, 0, stream>>>(out_proj_w, woutb, n);
    n = DFFN * DMODEL;
    cvt_bf16<<<(n + 255) / 256, 256, 0, stream>>>(w1, w1b, n);
    n = DMODEL * DFFN;
    cvt_bf16<<<(n + 255) / 256, 256, 0, stream>>>(w2, w2b, n);
  }

  // ---- in-proj: zx[8192,2192] = u @ in_proj_w^T (shared by fwd & bwd) ----
  gemm_bt<0><<<dim3(DPROJP / 128, NTOK / 128), 256, 0, stream>>>(u_bf, winb, zx, nullptr, DMODEL, DPROJ);

  // ---- dt (softplus), conv+silu, both directions ----
  dt_softplus<<<(2 * NTOK * NHEADS + 255) / 256, 256, 0, stream>>>(zx, dt_bias, dtf, dtb);
  conv_silu<<<dim3((NTOK * CONVDIM + 255) / 256, 2), 256, 0, stream>>>(zx, conv_w, conv_b, xcf, xcb);

  // ---- chunked SSD: 256 blocks = (dir,b,h) ----
  ssd_chunk<<<256, 256, 0, stream>>>(xcf, xcb, dtf, dtb, A_log, Dp, yf, yb);

  // ---- gate + RMS norm -> bf16 [16384,1024] ----
  gate_rms<<<2 * NTOK, 256, 0, stream>>>(yf, yb, zx, norm_w, gbf);

  // ---- out-proj: mo[16384,512] = g @ out_proj_w^T ----
  gemm_bt<0><<<dim3(DMODEL / 128, 2 * NTOK / 128), 256, 0, stream>>>(gbf, woutb, mo, nullptr, DINNER, DMODEL);

  // ---- combine + first layernorm ----
  combine_ln<<<NTOK, 256, 0, stream>>>(mo, item_emb, ln_w, ln_b, hln, hbf);

  // ---- FFN ----
  gemm_bt<1><<<dim3(DFFN / 128, NTOK / 128), 256, 0, stream>>>(hbf, w1b, h1b, b1, DMODEL, DFFN);
  gemm_bt<0><<<dim3(DMODEL / 128, NTOK / 128), 256, 0, stream>>>(h1b, w2b, f2, b2, DFFN, DMODEL);

  // ---- final layernorm -> d_out ----
  final_ln<<<NTOK, 256, 0, stream>>>(f2, hln, fln_w, fln_b, outp);

  (void)in_sizes; (void)n_in; (void)out_size; (void)ws_size;
}

// Round 3
// 465.025 us; speedup vs baseline: 1.9456x; 1.0806x over previous
//
#include <hip/hip_runtime.h>
#include <math.h>

#define SEQ     1024
#define NBATCH  8
#define NTOK    8192        // NBATCH*SEQ
#define DMODEL  512
#define DINNER  1024
#define NHEADS  16
#define DPROJ   2192
#define DPROJP  2304        // padded to multiple of 128
#define CONVDIM 1152
#define DFFN    2048

typedef short bf16x8 __attribute__((ext_vector_type(8)));
typedef float f32x4  __attribute__((ext_vector_type(4)));

__device__ inline unsigned short f2bf(float f) {
  union { float f; unsigned int u; } v; v.f = f;
  unsigned int u = v.u;
  return (unsigned short)((u + 0x7FFFu + ((u >> 16) & 1u)) >> 16);
}
__device__ inline float bf2f(unsigned short s) {
  union { unsigned int u; float f; } v; v.u = ((unsigned int)s) << 16;
  return v.f;
}

// ---------------- bf16 conversion ----------------
__global__ __launch_bounds__(256) void cvt_bf16(const float* __restrict__ s,
                                                unsigned short* __restrict__ d, int n) {
  int i = blockIdx.x * 256 + threadIdx.x;
  if (i < n) d[i] = f2bf(s[i]);
}

__global__ __launch_bounds__(256) void cvt_bf16_pad(const float* __restrict__ s,
                                                    unsigned short* __restrict__ d,
                                                    int realrows, int cols, int padrows) {
  int i = blockIdx.x * 256 + threadIdx.x;
  if (i < padrows * cols) {
    int r = i / cols;
    d[i] = (r < realrows) ? f2bf(s[i]) : (unsigned short)0;
  }
}

// ---------------- bf16 MFMA GEMM: C[M,N] = A[M,K] @ B[N,K]^T ----------------
// MODE 0: fp32 store (+bias). MODE 1: bias+gelu -> bf16. MODE 2: bf16 store,
//         cols >= 2176 also stored fp32 to aux[row*16 + col-2176] (dt path).
template <int MODE>
__global__ __launch_bounds__(256)
void gemm_bt(const unsigned short* __restrict__ A, const unsigned short* __restrict__ B,
             void* __restrict__ Cout, const float* __restrict__ bias,
             float* __restrict__ aux, int K, int Nreal) {
  __shared__ unsigned short sA[128 * 32];
  __shared__ unsigned short sB[128 * 32];
  const int tid = threadIdx.x;
  const int bx = blockIdx.x, by = blockIdx.y;
  const int lane = tid & 63;
  const int wave = tid >> 6;
  const int wm = wave >> 1, wn = wave & 1;
  const int arow = tid >> 2;
  const int acol = (tid & 3) << 3;

  const unsigned short* pA = A + (size_t)(by * 128 + arow) * K + acol;
  const unsigned short* pB = B + (size_t)(bx * 128 + arow) * K + acol;
  const size_t stride64 = (size_t)64 * K;

  f32x4 acc[4][4];
#pragma unroll
  for (int i = 0; i < 4; i++)
#pragma unroll
    for (int j = 0; j < 4; j++) { f32x4 z = {0.f, 0.f, 0.f, 0.f}; acc[i][j] = z; }

  const int lrow = lane & 15;
  const int lkq = (lane >> 4) << 3;

  for (int k0 = 0; k0 < K; k0 += 32) {
    uint4 a0 = *(const uint4*)pA;
    uint4 a1 = *(const uint4*)(pA + stride64);
    uint4 b0 = *(const uint4*)pB;
    uint4 b1 = *(const uint4*)(pB + stride64);
    pA += 32; pB += 32;
    __syncthreads();
    *(uint4*)&sA[tid * 8] = a0;
    *(uint4*)&sA[tid * 8 + 2048] = a1;
    *(uint4*)&sB[tid * 8] = b0;
    *(uint4*)&sB[tid * 8 + 2048] = b1;
    __syncthreads();
    bf16x8 af[4], bfr[4];
#pragma unroll
    for (int mi = 0; mi < 4; mi++)
      af[mi] = *(const bf16x8*)&sA[(wm * 64 + mi * 16 + lrow) * 32 + lkq];
#pragma unroll
    for (int ni = 0; ni < 4; ni++)
      bfr[ni] = *(const bf16x8*)&sB[(wn * 64 + ni * 16 + lrow) * 32 + lkq];
#pragma unroll
    for (int mi = 0; mi < 4; mi++)
#pragma unroll
      for (int ni = 0; ni < 4; ni++)
        acc[mi][ni] = __builtin_amdgcn_mfma_f32_16x16x32_bf16(af[mi], bfr[ni], acc[mi][ni], 0, 0, 0);
  }

  const int row0 = by * 128 + wm * 64;
  const int col0 = bx * 128 + wn * 64;
#pragma unroll
  for (int mi = 0; mi < 4; mi++) {
#pragma unroll
    for (int ni = 0; ni < 4; ni++) {
      const int col = col0 + ni * 16 + lrow;
      if (col < Nreal) {
        const float bval = (MODE != 2 && bias) ? bias[col] : 0.f;
#pragma unroll
        for (int r = 0; r < 4; r++) {
          const int row = row0 + mi * 16 + ((lane >> 4) << 2) + r;
          float v = acc[mi][ni][r] + bval;
          if (MODE == 1) {
            float g = 0.5f * v * (1.f + erff(v * 0.7071067811865476f));
            ((unsigned short*)Cout)[(size_t)row * Nreal + col] = f2bf(g);
          } else if (MODE == 2) {
            ((unsigned short*)Cout)[(size_t)row * Nreal + col] = f2bf(v);
            if (col >= 2176) aux[(size_t)row * 16 + (col - 2176)] = v;
          } else {
            ((float*)Cout)[(size_t)row * Nreal + col] = v;
          }
        }
      }
    }
  }
}

// ---------------- dt = softplus(zdt + dt_bias) (both dirs) ----------------
__global__ __launch_bounds__(256)
void dt_softplus(const float* __restrict__ zdt, const float* __restrict__ dt_bias,
                 float* __restrict__ dtf, float* __restrict__ dtb) {
  int i = blockIdx.x * 256 + threadIdx.x;
  if (i >= 2 * NTOK * NHEADS) return;
  int dir = (i >= NTOK * NHEADS) ? 1 : 0;
  int r = i - dir * NTOK * NHEADS;
  int h = r & 15, bt = r >> 4;
  int b = bt >> 10, t = bt & 1023;
  int srow = (b << 10) + (dir ? (1023 - t) : t);
  float v = zdt[(size_t)srow * 16 + h] + dt_bias[h];
  float dt = (v > 20.f) ? v : log1pf(expf(v));
  (dir ? dtb : dtf)[bt * 16 + h] = dt;
}

// ---------------- sliding-window causal dw-conv (k=4) + silu, BOTH dirs ----------------
// bwd output at t'=1026-s uses rows {s..s-3} with reversed taps -> one sweep serves both.
__global__ __launch_bounds__(256)
void conv_silu_bf(const unsigned short* __restrict__ zxb, const float* __restrict__ cw,
                  const float* __restrict__ cb,
                  unsigned short* __restrict__ xcf, unsigned short* __restrict__ xcb) {
  const int tid = threadIdx.x;
  const int c = blockIdx.x * 128 + (tid & 127);     // channel 0..1151
  const int b = blockIdx.y;
  const int seg = blockIdx.z * 2 + (tid >> 7);      // 0..7 (128 steps each)
  const int t0 = seg << 7;
  const float w0 = cw[c * 4 + 0], w1 = cw[c * 4 + 1], w2 = cw[c * 4 + 2], w3 = cw[c * 4 + 3];
  const float bias = cb[c];
  const unsigned short* src = zxb + (size_t)(b << 10) * DPROJ + DINNER + c;
  unsigned short* dstf = xcf + (size_t)(b << 10) * CONVDIM + c;
  unsigned short* dstb = xcb + (size_t)(b << 10) * CONVDIM + c;
  float r0 = 0.f, r1 = 0.f, r2 = 0.f;               // rows s-3, s-2, s-1
  if (t0 >= 3) {
    r0 = bf2f(src[(size_t)(t0 - 3) * DPROJ]);
    r1 = bf2f(src[(size_t)(t0 - 2) * DPROJ]);
    r2 = bf2f(src[(size_t)(t0 - 1) * DPROJ]);
  }
  for (int s = t0; s < t0 + 128; s++) {
    float x = bf2f(src[(size_t)s * DPROJ]);
    float vf = bias + w0 * r0 + w1 * r1 + w2 * r2 + w3 * x;
    dstf[(size_t)s * CONVDIM] = f2bf(vf / (1.f + expf(-vf)));
    int tp = 1026 - s;
    if (tp <= 1023) {                               // s >= 3
      float vb = bias + w0 * x + w1 * r2 + w2 * r1 + w3 * r0;
      dstb[(size_t)tp * CONVDIM] = f2bf(vb / (1.f + expf(-vb)));
    }
    r0 = r1; r1 = r2; r2 = x;
  }
  if (seg == 7) {
    // window: r0=row1021, r1=row1022, r2=row1023; emit bwd t' = 2,1,0
    float v2 = bias + w1 * r2 + w2 * r1 + w3 * r0;
    float v1 = bias + w2 * r2 + w3 * r1;
    float v0 = bias + w3 * r2;
    dstb[(size_t)2 * CONVDIM] = f2bf(v2 / (1.f + expf(-v2)));
    dstb[(size_t)1 * CONVDIM] = f2bf(v1 / (1.f + expf(-v1)));
    dstb[0] = f2bf(v0 / (1.f + expf(-v0)));
  }
}

// ---------------- chunked SSD: one block per (dir,b,h), 16 chunks of L=64 ----------------
__global__ __launch_bounds__(256)
void ssd_chunk(const unsigned short* __restrict__ xcf, const unsigned short* __restrict__ xcb,
               const float* __restrict__ dtf, const float* __restrict__ dtb,
               const float* __restrict__ A_log, const float* __restrict__ Dp,
               float* __restrict__ yf, float* __restrict__ yb) {
  const int blk = blockIdx.x;
  const int dir = blk >> 7;
  const int b = (blk >> 4) & 7;
  const int h = blk & 15;
  const unsigned short* xc = dir ? xcb : xcf;
  const float* dtp = dir ? dtb : dtf;
  float* yo = dir ? yb : yf;
  const float A = -expf(A_log[h]);
  const float Dh = Dp[h];
  const int tid = threadIdx.x;
  const int lane = tid & 63;
  const int w = tid >> 6;          // wave 0..3 -> 16-row output stripe
  const int lrow = lane & 15;
  const int quad = lane >> 4;
  const int lk8 = quad << 3;
  const int bS = b << 10;

  // bf16 tiles, row stride 72
  __shared__ unsigned short Cb[64 * 72];   // [i][n]
  __shared__ unsigned short Bb[64 * 72];   // [s][n]
  __shared__ unsigned short Xt[64 * 72];   // [p][s]
  __shared__ unsigned short Bw[64 * 72];   // [n][s]  (decay/dt weighted)
  __shared__ unsigned short Mb[64 * 72];   // [i][s]  (masked)
  __shared__ unsigned short Hb[64 * 72];   // [p][n]  (h_init, bf16)

  f32x4 hacc[4];                           // h[p= w*16+quad*4+r][n= j*16+lrow]
#pragma unroll
  for (int j = 0; j < 4; j++) { f32x4 z = {0.f, 0.f, 0.f, 0.f}; hacc[j] = z; }

  for (int c = 0; c < 16; c++) {
    const int t0 = c << 6;
    __syncthreads();                       // protect LDS from previous chunk's readers

    // stage h_init -> LDS (bf16)
#pragma unroll
    for (int j = 0; j < 4; j++)
#pragma unroll
      for (int r = 0; r < 4; r++)
        Hb[(w * 16 + quad * 4 + r) * 72 + j * 16 + lrow] = f2bf(hacc[j][r]);

    // stage x/B/C rows t0..t0+63 -> LDS (bf16 source)
#pragma unroll
    for (int pass = 0; pass < 2; pass++) {
      int i = pass * 256 + tid;
      int s = i >> 3, cc = i & 7;          // 8 ch-chunks of 8 per row
      const unsigned short* rowp = xc + (size_t)(bS + t0 + s) * CONVDIM;
      uint4 vx = *(const uint4*)(rowp + h * 64 + cc * 8);
      uint4 vb = *(const uint4*)(rowp + 1024 + cc * 8);
      uint4 vc = *(const uint4*)(rowp + 1088 + cc * 8);
      *(uint4*)&Bb[s * 72 + cc * 8] = vb;
      *(uint4*)&Cb[s * 72 + cc * 8] = vc;
      const unsigned short* xp = (const unsigned short*)&vx;
#pragma unroll
      for (int k = 0; k < 8; k++) Xt[(cc * 8 + k) * 72 + s] = xp[k];
    }
    float dtl = dtp[(bS + t0 + lane) * 16 + h];   // lane l holds dt_{t0+l}
    __syncthreads();

    // per-wave inclusive prefix scan of dt over 64 lanes
    float v = dtl;
#pragma unroll
    for (int off = 1; off < 64; off <<= 1) {
      float o = __shfl_up(v, off);
      if (lane >= off) v += o;
    }
    const float Lv = A * v;                 // L_lane (<=0)
    const float ev = expf(Lv);
    const float LL = __shfl(Lv, 63);
    const float wv = dtl * expf(LL - Lv);   // state weight for s=lane

    // Bw[n][s] = B[s][n] * wv_s   (s = lane, n = w + 4k)
#pragma unroll
    for (int k = 0; k < 16; k++) {
      int n = w + 4 * k;
      Bw[n * 72 + lane] = f2bf(bf2f(Bb[lane * 72 + n]) * wv);
    }

    // GEMM1: M1[i in stripe][s]
    f32x4 m1[4];
#pragma unroll
    for (int j = 0; j < 4; j++) { f32x4 z = {0.f, 0.f, 0.f, 0.f}; m1[j] = z; }
#pragma unroll
    for (int kq = 0; kq < 2; kq++) {
      bf16x8 af = *(const bf16x8*)&Cb[(w * 16 + lrow) * 72 + kq * 32 + lk8];
#pragma unroll
      for (int j = 0; j < 4; j++) {
        bf16x8 bf = *(const bf16x8*)&Bb[(j * 16 + lrow) * 72 + kq * 32 + lk8];
        m1[j] = __builtin_amdgcn_mfma_f32_16x16x32_bf16(af, bf, m1[j], 0, 0, 0);
      }
    }
    // mask + decay -> Mb
#pragma unroll
    for (int r = 0; r < 4; r++) {
      int i = w * 16 + quad * 4 + r;
      float Li = __shfl(Lv, i);
#pragma unroll
      for (int j = 0; j < 4; j++) {
        int s = j * 16 + lrow;
        float Ls = __shfl(Lv, s);
        float ds = __shfl(dtl, s);
        float val = (s <= i) ? m1[j][r] * expf(Li - Ls) * ds : 0.f;
        Mb[i * 72 + s] = f2bf(val);
      }
    }
    __syncthreads();

    // GEMM2: Y = M@X ; T = C@H^T ; S = Xt@Bw^T
    f32x4 Y[4], T[4], S[4];
#pragma unroll
    for (int j = 0; j < 4; j++) {
      f32x4 z = {0.f, 0.f, 0.f, 0.f};
      Y[j] = z; T[j] = z; S[j] = z;
    }
#pragma unroll
    for (int kq = 0; kq < 2; kq++) {
      bf16x8 am = *(const bf16x8*)&Mb[(w * 16 + lrow) * 72 + kq * 32 + lk8];
      bf16x8 ac = *(const bf16x8*)&Cb[(w * 16 + lrow) * 72 + kq * 32 + lk8];
      bf16x8 ax = *(const bf16x8*)&Xt[(w * 16 + lrow) * 72 + kq * 32 + lk8];
#pragma unroll
      for (int j = 0; j < 4; j++) {
        bf16x8 bx = *(const bf16x8*)&Xt[(j * 16 + lrow) * 72 + kq * 32 + lk8];
        bf16x8 bh = *(const bf16x8*)&Hb[(j * 16 + lrow) * 72 + kq * 32 + lk8];
        bf16x8 bw = *(const bf16x8*)&Bw[(j * 16 + lrow) * 72 + kq * 32 + lk8];
        Y[j] = __builtin_amdgcn_mfma_f32_16x16x32_bf16(am, bx, Y[j], 0, 0, 0);
        T[j] = __builtin_amdgcn_mfma_f32_16x16x32_bf16(ac, bh, T[j], 0, 0, 0);
        S[j] = __builtin_amdgcn_mfma_f32_16x16x32_bf16(ax, bw, S[j], 0, 0, 0);
      }
    }

    // combine + store Y, update h
    const float dtot = expf(LL);
#pragma unroll
    for (int r = 0; r < 4; r++) {
      int i = w * 16 + quad * 4 + r;
      float ei = __shfl(ev, i);
#pragma unroll
      for (int j = 0; j < 4; j++) {
        int p = j * 16 + lrow;
        float yv = Y[j][r] + ei * T[j][r] + Dh * bf2f(Xt[p * 72 + i]);
        yo[(size_t)(bS + t0 + i) * DINNER + h * 64 + p] = yv;
      }
    }
#pragma unroll
    for (int j = 0; j < 4; j++)
#pragma unroll
      for (int r = 0; r < 4; r++)
        hacc[j][r] = dtot * hacc[j][r] + S[j][r];
  }
}

// ---------------- block reduction (256 threads, 4 waves) ----------------
__device__ inline float2 block_sum2_256(float a, float b) {
#pragma unroll
  for (int o = 32; o >= 1; o >>= 1) { a += __shfl_xor(a, o); b += __shfl_xor(b, o); }
  __shared__ float ra[4], rb[4];
  const int lane = threadIdx.x & 63, w = threadIdx.x >> 6;
  if (lane == 0) { ra[w] = a; rb[w] = b; }
  __syncthreads();
  float2 out;
  out.x = ra[0] + ra[1] + ra[2] + ra[3];
  out.y = rb[0] + rb[1] + rb[2] + rb[3];
  return out;
}

// ---------------- g = y*silu(z); RMS-norm; -> bf16 ----------------
__global__ __launch_bounds__(256)
void gate_rms(const float* __restrict__ yf, const float* __restrict__ yb,
              const unsigned short* __restrict__ zxb, const float* __restrict__ nw,
              unsigned short* __restrict__ gbf) {
  const int r = blockIdx.x;          // 0..16383 (dir-major)
  const int dir = r >> 13;
  const int bt = r & (NTOK - 1);
  const int b = bt >> 10, t = bt & 1023;
  const int zrow = (b << 10) + (dir ? (1023 - t) : t);
  const float* y = (dir ? yb : yf) + (size_t)bt * DINNER;
  const unsigned short* z = zxb + (size_t)zrow * DPROJ;
  const int tid = threadIdx.x;
  float4 yv = *(const float4*)(y + tid * 4);
  ushort4 zv4 = *(const ushort4*)(z + tid * 4);
  float z0 = bf2f(zv4.x), z1 = bf2f(zv4.y), z2 = bf2f(zv4.z), z3 = bf2f(zv4.w);
  float4 g;
  g.x = yv.x * (z0 / (1.f + expf(-z0)));
  g.y = yv.y * (z1 / (1.f + expf(-z1)));
  g.z = yv.z * (z2 / (1.f + expf(-z2)));
  g.w = yv.w * (z3 / (1.f + expf(-z3)));
  float2 sr = block_sum2_256(g.x * g.x + g.y * g.y + g.z * g.z + g.w * g.w, 0.f);
  float scale = rsqrtf(sr.x * (1.f / 1024.f) + 1e-5f);
  float4 wv = *(const float4*)(nw + tid * 4);
  unsigned short* o = gbf + (size_t)r * DINNER + tid * 4;
  o[0] = f2bf(g.x * scale * wv.x);
  o[1] = f2bf(g.y * scale * wv.y);
  o[2] = f2bf(g.z * scale * wv.z);
  o[3] = f2bf(g.w * scale * wv.w);
}

// ---------------- h = fwd + 0.5*bwd + u; layernorm -> fp32 + bf16 ----------------
__global__ __launch_bounds__(256)
void combine_ln(const float* __restrict__ mo, const float* __restrict__ u,
                const float* __restrict__ w, const float* __restrict__ bias,
                float* __restrict__ hln, unsigned short* __restrict__ hbf) {
  const int bt = blockIdx.x;
  const int tid = threadIdx.x;
  const float2 mf = *(const float2*)(mo + (size_t)bt * DMODEL + tid * 2);
  const float2 mb = *(const float2*)(mo + (size_t)(NTOK + bt) * DMODEL + tid * 2);
  const float2 uu = *(const float2*)(u + (size_t)bt * DMODEL + tid * 2);
  float vx = mf.x + 0.5f * mb.x + uu.x;
  float vy = mf.y + 0.5f * mb.y + uu.y;
  float2 sr = block_sum2_256(vx + vy, vx * vx + vy * vy);
  float mean = sr.x * (1.f / 512.f);
  float var = sr.y * (1.f / 512.f) - mean * mean;
  float inv = rsqrtf(var + 1e-12f);
  float2 wv = *(const float2*)(w + tid * 2);
  float2 bv = *(const float2*)(bias + tid * 2);
  float ox = (vx - mean) * inv * wv.x + bv.x;
  float oy = (vy - mean) * inv * wv.y + bv.y;
  *(float2*)(hln + (size_t)bt * DMODEL + tid * 2) = make_float2(ox, oy);
  hbf[(size_t)bt * DMODEL + tid * 2] = f2bf(ox);
  hbf[(size_t)bt * DMODEL + tid * 2 + 1] = f2bf(oy);
}

// ---------------- out = layernorm(f2 + hln) ----------------
__global__ __launch_bounds__(256)
void final_ln(const float* __restrict__ f2, const float* __restrict__ hln,
              const float* __restrict__ w, const float* __restrict__ bias,
              float* __restrict__ outp) {
  const int bt = blockIdx.x;
  const int tid = threadIdx.x;
  const float2 a = *(const float2*)(f2 + (size_t)bt * DMODEL + tid * 2);
  const float2 h = *(const float2*)(hln + (size_t)bt * DMODEL + tid * 2);
  float vx = a.x + h.x;
  float vy = a.y + h.y;
  float2 sr = block_sum2_256(vx + vy, vx * vx + vy * vy);
  float mean = sr.x * (1.f / 512.f);
  float var = sr.y * (1.f / 512.f) - mean * mean;
  float inv = rsqrtf(var + 1e-12f);
  float2 wv = *(const float2*)(w + tid * 2);
  float2 bv = *(const float2*)(bias + tid * 2);
  *(float2*)(outp + (size_t)bt * DMODEL + tid * 2) =
      make_float2((vx - mean) * inv * wv.x + bv.x, (vy - mean) * inv * wv.y + bv.y);
}

extern "C" void kernel_launch(void* const* d_in, const int* in_sizes, int n_in,
                              void* d_out, int out_size, void* d_ws, size_t ws_size,
                              hipStream_t stream) {
  const float* item_emb   = (const float*)d_in[0];
  const float* in_proj_w  = (const float*)d_in[3];
  const float* conv_w     = (const float*)d_in[4];
  const float* conv_b     = (const float*)d_in[5];
  const float* dt_bias    = (const float*)d_in[6];
  const float* A_log      = (const float*)d_in[7];
  const float* Dp         = (const float*)d_in[8];
  const float* norm_w     = (const float*)d_in[9];
  const float* out_proj_w = (const float*)d_in[10];
  const float* ln_w       = (const float*)d_in[11];
  const float* ln_b       = (const float*)d_in[12];
  const float* w1         = (const float*)d_in[13];
  const float* b1         = (const float*)d_in[14];
  const float* w2         = (const float*)d_in[15];
  const float* b2         = (const float*)d_in[16];
  const float* fln_w      = (const float*)d_in[17];
  const float* fln_b      = (const float*)d_in[18];
  float* outp = (float*)d_out;
  char* ws = (char*)d_ws;

  // ---- workspace layout (bytes) ----
  const size_t o_ubf  = 0;                 // [8192,512]  bf16    8,388,608
  const size_t o_win  = 8388608;           // [2304,512]  bf16    2,359,296
  const size_t o_wout = 10747904;          // [512,1024]  bf16    1,048,576
  const size_t o_w1   = 11796480;          // [2048,512]  bf16    2,097,152
  const size_t o_w2   = 13893632;          // [512,2048]  bf16    2,097,152
  const size_t o_dtf  = 15990784;          // [8192,16]   f32       524,288
  const size_t o_dtb  = 16515072;
  const size_t o_zdt  = 17039360;          // [8192,16]   f32       524,288
  const size_t o_zxb  = 17563648;          // [8192,2192] bf16   35,913,728
  const size_t o_xcf  = 53477376;          // [8192,1152] bf16   18,874,368
  const size_t o_xcb  = 72351744;
  const size_t o_yf   = 91226112;          // [8192,1024] f32    33,554,432
  const size_t o_yb   = 124780544;         //                    total 158,334,976
  // phase-2 aliases (regions dead by the time these are written)
  const size_t o_gbf  = o_xcf;             // [16384,1024] bf16  (xcf/xcb dead)
  const size_t o_mo   = o_zxb;             // [16384,512]  f32   (zxb dead)
  const size_t o_hln  = o_yf;              // [8192,512]   f32   (yf dead)
  const size_t o_hbf  = o_ubf;             // [8192,512]   bf16  (u_bf dead)
  const size_t o_h1   = o_yb;              // [8192,2048]  bf16  (yb dead)
  const size_t o_f2   = o_gbf;             // [8192,512]   f32   (gbf dead)

  unsigned short* u_bf  = (unsigned short*)(ws + o_ubf);
  unsigned short* winb  = (unsigned short*)(ws + o_win);
  unsigned short* woutb = (unsigned short*)(ws + o_wout);
  unsigned short* w1b   = (unsigned short*)(ws + o_w1);
  unsigned short* w2b   = (unsigned short*)(ws + o_w2);
  float* dtf = (float*)(ws + o_dtf);
  float* dtb = (float*)(ws + o_dtb);
  float* zdt = (float*)(ws + o_zdt);
  unsigned short* zxb = (unsigned short*)(ws + o_zxb);
  unsigned short* xcf = (unsigned short*)(ws + o_xcf);
  unsigned short* xcb = (unsigned short*)(ws + o_xcb);
  float* yf  = (float*)(ws + o_yf);
  float* yb  = (float*)(ws + o_yb);
  unsigned short* gbf = (unsigned short*)(ws + o_gbf);
  float* mo  = (float*)(ws + o_mo);
  float* hln = (float*)(ws + o_hln);
  unsigned short* hbf = (unsigned short*)(ws + o_hbf);
  unsigned short* h1b = (unsigned short*)(ws + o_h1);
  float* f2  = (float*)(ws + o_f2);

  // ---- bf16 conversions ----
  {
    int n = NTOK * DMODEL;
    cvt_bf16<<<(n + 255) / 256, 256, 0, stream>>>(item_emb, u_bf, n);
    cvt_bf16_pad<<<(DPROJP * DMODEL + 255) / 256, 256, 0, stream>>>(in_proj_w, winb, DPROJ, DMODEL, DPROJP);
    n = DMODEL * DINNER;
    cvt_bf16<<<(n + 255) / 256, 256, 0, stream>>>(out_proj_w, woutb, n);
    n = DFFN * DMODEL;
    cvt_bf16<<<(n + 255) / 256, 256, 0, stream>>>(w1, w1b, n);
    n = DMODEL * DFFN;
    cvt_bf16<<<(n + 255) / 256, 256, 0, stream>>>(w2, w2b, n);
  }

  // ---- in-proj: zxb[8192,2192](bf16) = u @ in_proj_w^T ; dt cols also fp32 -> zdt ----
  gemm_bt<2><<<dim3(DPROJP / 128, NTOK / 128), 256, 0, stream>>>(u_bf, winb, zxb, nullptr, zdt, DMODEL, DPROJ);

  // ---- dt (softplus), conv+silu both dirs in one sweep ----
  dt_softplus<<<(2 * NTOK * NHEADS + 255) / 256, 256, 0, stream>>>(zdt, dt_bias, dtf, dtb);
  conv_silu_bf<<<dim3(9, NBATCH, 4), 256, 0, stream>>>(zxb, conv_w, conv_b, xcf, xcb);

  // ---- chunked SSD: 256 blocks = (dir,b,h) ----
  ssd_chunk<<<256, 256, 0, stream>>>(xcf, xcb, dtf, dtb, A_log, Dp, yf, yb);

  // ---- gate + RMS norm -> bf16 [16384,1024] ----
  gate_rms<<<2 * NTOK, 256, 0, stream>>>(yf, yb, zxb, norm_w, gbf);

  // ---- out-proj: mo[16384,512] = g @ out_proj_w^T ----
  gemm_bt<0><<<dim3(DMODEL / 128, 2 * NTOK / 128), 256, 0, stream>>>(gbf, woutb, mo, nullptr, nullptr, DINNER, DMODEL);

  // ---- combine + first layernorm ----
  combine_ln<<<NTOK, 256, 0, stream>>>(mo, item_emb, ln_w, ln_b, hln, hbf);

  // ---- FFN ----
  gemm_bt<1><<<dim3(DFFN / 128, NTOK / 128), 256, 0, stream>>>(hbf, w1b, h1b, b1, nullptr, DMODEL, DFFN);
  gemm_bt<0><<<dim3(DMODEL / 128, NTOK / 128), 256, 0, stream>>>(h1b, w2b, f2, b2, nullptr, DFFN, DMODEL);

  // ---- final layernorm -> d_out ----
  final_ln<<<NTOK, 256, 0, stream>>>(f2, hln, fln_w, fln_b, outp);

  (void)in_sizes; (void)n_in; (void)out_size; (void)ws_size;
}